// Round 22
// baseline (79.068 us; speedup 1.0000x reference)
//
#include <hip/hip_runtime.h>
#include <cstdint>

#define BB 256
#define NN 128
#define DD 512
#define HH 512

typedef __attribute__((ext_vector_type(8))) short bf16x8;
typedef __attribute__((ext_vector_type(16))) float f32x16;
typedef unsigned short u16;

static __device__ __forceinline__ u16 f2bf(float f) {
    union { float f; uint32_t u; } v; v.f = f;
    uint32_t u = v.u;
    return (u16)((u + 0x7FFFu + ((u >> 16) & 1u)) >> 16);
}

static __device__ __forceinline__ void gload16(const u16* g, u16* l) {
    __builtin_amdgcn_global_load_lds((const __attribute__((address_space(1))) void*)g,
                                     (__attribute__((address_space(3))) void*)l, 16, 0, 0);
}

// ---------------- W fp32 -> bf16 TRANSPOSED chunk-major: Wt[kc][h][8]  (R17-verified) ----------------
__global__ __launch_bounds__(256) void wconv_kernel(const float* __restrict__ W, u16* __restrict__ Wt) {
    int idx = (blockIdx.x * 256 + threadIdx.x) * 4;
    int h = idx >> 9, d = idx & 511;
    float4 v = *(const float4*)(W + idx);
    ushort4 o;
    o.x = f2bf(v.x); o.y = f2bf(v.y); o.z = f2bf(v.z); o.w = f2bf(v.w);
    *(ushort4*)(Wt + ((size_t)(d >> 3) * HH + h) * 8 + (d & 7)) = o;
}

// ---------------- Xagg = (I + A_norm) @ X -> HBM bf16  (R12/R17-verified) ----------------
__global__ __launch_bounds__(512) void agg_kernel(const float* __restrict__ X, const float* __restrict__ A,
                                                  u16* __restrict__ Xagg) {
    __shared__ __align__(16) char smem[163840];
    u16* Ms = (u16*)smem;                 // [128 i][128 m], chunk c' = c ^ (i&15)
    u16* Xt = (u16*)(smem + 32768);       // [512 d][128 m], chunk c' = c ^ ((d>>2)&7)

    const int t = threadIdx.x;
    const int lane = t & 63, w = t >> 6, l31 = lane & 31, lh = lane >> 5;
    const int batch = blockIdx.x;
    const int wm = w >> 2, wn = w & 3;

    {
        const int row = t >> 2, seg = t & 3;
        const float* Ag = A + (size_t)batch * NN * NN + row * NN + seg * 32;
        float4 a[8];
        #pragma unroll
        for (int j = 0; j < 8; ++j) a[j] = *(const float4*)(Ag + j * 4);
        float s = 0.f;
        #pragma unroll
        for (int j = 0; j < 8; ++j) s += a[j].x + a[j].y + a[j].z + a[j].w;
        s += __shfl_xor(s, 1);
        s += __shfl_xor(s, 2);
        const float inv = 1.0f / (s + 1e-6f);
        #pragma unroll
        for (int c2 = 0; c2 < 4; ++c2) {
            u16 tmp[8];
            const float* pe = (const float*)&a[c2 * 2];
            #pragma unroll
            for (int e = 0; e < 8; ++e) {
                int m = seg * 32 + c2 * 8 + e;
                tmp[e] = f2bf(pe[e] * inv + (m == row ? 1.0f : 0.0f));
            }
            int c = seg * 4 + c2;
            *(uint4*)(Ms + row * 128 + ((c ^ (row & 15)) << 3)) = *(const uint4*)tmp;
        }
    }

    {
        const float* Xg = X + (size_t)batch * NN * DD;
        #pragma unroll
        for (int it = 0; it < 32; ++it) {
            int q = it * 512 + t;
            int m = q >> 7, c4 = q & 127;
            float4 v = *(const float4*)(Xg + (size_t)m * DD + c4 * 4);
            float fv[4] = {v.x, v.y, v.z, v.w};
            #pragma unroll
            for (int j = 0; j < 4; ++j) {
                int d = c4 * 4 + j;
                Xt[d * 128 + (((m >> 3) ^ ((d >> 2) & 7)) << 3) + (m & 7)] = f2bf(fv[j]);
            }
        }
    }
    __syncthreads();

    u16* Og = Xagg + (size_t)batch * NN * DD;
    #pragma unroll
    for (int dh = 0; dh < 2; ++dh) {
        f32x16 acc1[2][2];
        #pragma unroll
        for (int fi = 0; fi < 2; ++fi)
            #pragma unroll
            for (int fd = 0; fd < 2; ++fd)
                #pragma unroll
                for (int r = 0; r < 16; ++r)
                    acc1[fi][fd][r] = 0.f;

        #pragma unroll
        for (int ksl = 0; ksl < 8; ++ksl) {
            const int kc = ksl * 2 + lh;
            bf16x8 af[2], bx[2];
            #pragma unroll
            for (int fi = 0; fi < 2; ++fi) {
                int i = wm * 64 + fi * 32 + l31;
                af[fi] = *(const bf16x8*)(Ms + i * 128 + ((kc ^ (i & 15)) << 3));
            }
            #pragma unroll
            for (int fd = 0; fd < 2; ++fd) {
                int d = dh * 256 + wn * 64 + fd * 32 + l31;
                bx[fd] = *(const bf16x8*)(Xt + d * 128 + ((kc ^ ((d >> 2) & 7)) << 3));
            }
            #pragma unroll
            for (int fi = 0; fi < 2; ++fi)
                #pragma unroll
                for (int fd = 0; fd < 2; ++fd)
                    acc1[fi][fd] = __builtin_amdgcn_mfma_f32_32x32x16_bf16(af[fi], bx[fd], acc1[fi][fd], 0, 0, 0);
        }

        #pragma unroll
        for (int fi = 0; fi < 2; ++fi)
            #pragma unroll
            for (int r = 0; r < 16; ++r) {
                int i = wm * 64 + fi * 32 + (r & 3) + 8 * (r >> 2) + 4 * lh;
                #pragma unroll
                for (int fd = 0; fd < 2; ++fd) {
                    int d = dh * 256 + wn * 64 + fd * 32 + l31;
                    Og[(size_t)i * DD + d] = f2bf(acc1[fi][fd][r]);
                }
            }
    }
}

// ---------------- out = sigmoid(LN( Xagg @ W^T + bias )) ----------------
// grid 1024 (M-tile 32), 512 thr = 8 waves; wave w -> h strip [64w, 64w+64) (2 frags).
// X-tile [32 m][512 k] = 32 KB LDS staged once; W direct from transposed Wt
// (coalesced 512B frags, L2; 0 conflicts); zero K-loop barriers.
// __launch_bounds__(512,4): VGPR cap 128 >= ~80 live (acc[2]=32) -> no spill,
// and 4 waves/EU = 16 waves/CU = 2 co-resident blocks (2 x 32 KB LDS fits) —
// +33% TLP over R20's 12 waves/CU to cover the ~300-cyc Wt L2 chain.
__global__ __launch_bounds__(512, 4) void gemm_ln_kernel(const u16* __restrict__ Xagg, const u16* __restrict__ Wt,
                                                         const float* __restrict__ bias, const float* __restrict__ lnw,
                                                         const float* __restrict__ lnb, float* __restrict__ out) {
    __shared__ __align__(16) char smem[32768];   // X tile; stats overlay after K-loop
    float* Pss = (float*)smem;                   // [8 w][32 row][2]
    float* musig = (float*)(smem + 2048);        // [32 row][2]

    const int t = threadIdx.x;
    const int lane = t & 63, w = t >> 6, l31 = lane & 31, lh = lane >> 5;
    const size_t rb = (size_t)blockIdx.x * 32;
    const u16* Xab = Xagg + rb * DD;

    float bias_v[2], lnw_v[2], lnb_v[2];
    #pragma unroll
    for (int fh = 0; fh < 2; ++fh) {
        int h = w * 64 + fh * 32 + l31;
        bias_v[fh] = bias[h];
        lnw_v[fh] = lnw[h];
        lnb_v[fh] = lnb[h];
    }

    // stage X tile once: linear LDS dest, inverse-swizzled source (c' = c ^ (m&15))
    #pragma unroll
    for (int it = 0; it < 4; ++it) {
        int q = it * 512 + t;
        int m = q >> 6, cp = q & 63;
        gload16(Xab + (size_t)m * DD + ((cp ^ (m & 15)) * 8), (u16*)smem + q * 8);
    }
    __syncthreads();   // drains gloads; X read-only hereafter

    f32x16 acc[2];
    #pragma unroll
    for (int fh = 0; fh < 2; ++fh)
        #pragma unroll
        for (int r = 0; r < 16; ++r)
            acc[fh][r] = 0.f;

    const u16* al = (const u16*)smem;
    #pragma unroll
    for (int st = 0; st < 32; ++st) {
        const int gc = st * 2 + lh;               // 16B k-chunk 0..63
        bf16x8 af = *(const bf16x8*)(al + (l31 * 64 + (gc ^ (l31 & 15))) * 8);
        bf16x8 bw[2];
        #pragma unroll
        for (int fh = 0; fh < 2; ++fh) {
            int h = w * 64 + fh * 32 + l31;
            bw[fh] = *(const bf16x8*)(Wt + ((size_t)gc * HH + h) * 8);
        }
        #pragma unroll
        for (int fh = 0; fh < 2; ++fh)
            acc[fh] = __builtin_amdgcn_mfma_f32_32x32x16_bf16(af, bw[fh], acc[fh], 0, 0, 0);
    }
    __syncthreads();   // X dead; overlay stats

    // bias + per-row stats over this wave's 64 h
    float rs[16], rss[16];
    #pragma unroll
    for (int r = 0; r < 16; ++r) {
        float a0 = acc[0][r] + bias_v[0];
        float a1 = acc[1][r] + bias_v[1];
        acc[0][r] = a0; acc[1][r] = a1;
        rs[r] = a0 + a1;
        rss[r] = a0 * a0 + a1 * a1;
    }
    #pragma unroll
    for (int msk = 1; msk <= 16; msk <<= 1)
        #pragma unroll
        for (int r = 0; r < 16; ++r) {
            rs[r] += __shfl_xor(rs[r], msk);
            rss[r] += __shfl_xor(rss[r], msk);
        }
    if (l31 == 0) {
        #pragma unroll
        for (int r = 0; r < 16; ++r) {
            int rl = (r & 3) + 8 * (r >> 2) + 4 * lh;
            float2 v; v.x = rs[r]; v.y = rss[r];
            *(float2*)(Pss + (w * 32 + rl) * 2) = v;
        }
    }
    __syncthreads();
    if (t < 32) {
        float s = 0.f, ss = 0.f;
        #pragma unroll
        for (int q = 0; q < 8; ++q) {
            float2 v = *(const float2*)(Pss + (q * 32 + t) * 2);
            s += v.x; ss += v.y;
        }
        float mean = s * (1.0f / 512.0f);
        float var = ss * (1.0f / 512.0f) - mean * mean;
        float2 mz; mz.x = mean; mz.y = rsqrtf(var + 1e-5f);
        *(float2*)(musig + t * 2) = mz;
    }
    __syncthreads();

    #pragma unroll
    for (int r = 0; r < 16; ++r) {
        int rl = (r & 3) + 8 * (r >> 2) + 4 * lh;
        float2 mz = *(const float2*)(musig + rl * 2);
        #pragma unroll
        for (int fh = 0; fh < 2; ++fh) {
            float xn = (acc[fh][r] - mz.x) * mz.y * lnw_v[fh] + lnb_v[fh];
            out[(rb + rl) * HH + w * 64 + fh * 32 + l31] = 1.0f / (1.0f + __expf(-xn));
        }
    }
}

extern "C" void kernel_launch(void* const* d_in, const int* in_sizes, int n_in,
                              void* d_out, int out_size, void* d_ws, size_t ws_size,
                              hipStream_t stream) {
    const float* X = (const float*)d_in[0];
    const float* A = (const float*)d_in[1];
    const float* W = (const float*)d_in[2];
    const float* bias = (const float*)d_in[3];
    const float* lnw = (const float*)d_in[4];
    const float* lnb = (const float*)d_in[5];
    float* out = (float*)d_out;

    u16* Xagg = (u16*)d_ws;                                  // B*N*D bf16 = 32 MB
    u16* Wt = (u16*)d_ws + (size_t)BB * NN * DD;             // transposed W bf16 = 512 KB

    hipLaunchKernelGGL(wconv_kernel, dim3(256), dim3(256), 0, stream, W, Wt);
    hipLaunchKernelGGL(agg_kernel, dim3(256), dim3(512), 0, stream, X, A, Xagg);
    hipLaunchKernelGGL(gemm_ln_kernel, dim3(1024), dim3(512), 0, stream, Xagg, Wt, bias, lnw, lnb, out);
}

// Round 23
// 72.548 us; speedup vs baseline: 1.0899x; 1.0899x over previous
//
#include <hip/hip_runtime.h>
#include <cstdint>

#define BB 256
#define NN 128
#define DD 512
#define HH 512

typedef __attribute__((ext_vector_type(8))) short bf16x8;
typedef __attribute__((ext_vector_type(16))) float f32x16;
typedef unsigned short u16;

static __device__ __forceinline__ u16 f2bf(float f) {
    union { float f; uint32_t u; } v; v.f = f;
    uint32_t u = v.u;
    return (u16)((u + 0x7FFFu + ((u >> 16) & 1u)) >> 16);
}

static __device__ __forceinline__ void gload16(const u16* g, u16* l) {
    __builtin_amdgcn_global_load_lds((const __attribute__((address_space(1))) void*)g,
                                     (__attribute__((address_space(3))) void*)l, 16, 0, 0);
}

// ---------------- W fp32 -> bf16 TRANSPOSED chunk-major: Wt[kc][h][8]  (R17-verified) ----------------
__global__ __launch_bounds__(256) void wconv_kernel(const float* __restrict__ W, u16* __restrict__ Wt) {
    int idx = (blockIdx.x * 256 + threadIdx.x) * 4;
    int h = idx >> 9, d = idx & 511;
    float4 v = *(const float4*)(W + idx);
    ushort4 o;
    o.x = f2bf(v.x); o.y = f2bf(v.y); o.z = f2bf(v.z); o.w = f2bf(v.w);
    *(ushort4*)(Wt + ((size_t)(d >> 3) * HH + h) * 8 + (d & 7)) = o;
}

// ---------------- Xagg = (I + A_norm) @ X -> HBM bf16  (R12/R17-verified) ----------------
__global__ __launch_bounds__(512) void agg_kernel(const float* __restrict__ X, const float* __restrict__ A,
                                                  u16* __restrict__ Xagg) {
    __shared__ __align__(16) char smem[163840];
    u16* Ms = (u16*)smem;                 // [128 i][128 m], chunk c' = c ^ (i&15)
    u16* Xt = (u16*)(smem + 32768);       // [512 d][128 m], chunk c' = c ^ ((d>>2)&7)

    const int t = threadIdx.x;
    const int lane = t & 63, w = t >> 6, l31 = lane & 31, lh = lane >> 5;
    const int batch = blockIdx.x;
    const int wm = w >> 2, wn = w & 3;

    {
        const int row = t >> 2, seg = t & 3;
        const float* Ag = A + (size_t)batch * NN * NN + row * NN + seg * 32;
        float4 a[8];
        #pragma unroll
        for (int j = 0; j < 8; ++j) a[j] = *(const float4*)(Ag + j * 4);
        float s = 0.f;
        #pragma unroll
        for (int j = 0; j < 8; ++j) s += a[j].x + a[j].y + a[j].z + a[j].w;
        s += __shfl_xor(s, 1);
        s += __shfl_xor(s, 2);
        const float inv = 1.0f / (s + 1e-6f);
        #pragma unroll
        for (int c2 = 0; c2 < 4; ++c2) {
            u16 tmp[8];
            const float* pe = (const float*)&a[c2 * 2];
            #pragma unroll
            for (int e = 0; e < 8; ++e) {
                int m = seg * 32 + c2 * 8 + e;
                tmp[e] = f2bf(pe[e] * inv + (m == row ? 1.0f : 0.0f));
            }
            int c = seg * 4 + c2;
            *(uint4*)(Ms + row * 128 + ((c ^ (row & 15)) << 3)) = *(const uint4*)tmp;
        }
    }

    {
        const float* Xg = X + (size_t)batch * NN * DD;
        #pragma unroll
        for (int it = 0; it < 32; ++it) {
            int q = it * 512 + t;
            int m = q >> 7, c4 = q & 127;
            float4 v = *(const float4*)(Xg + (size_t)m * DD + c4 * 4);
            float fv[4] = {v.x, v.y, v.z, v.w};
            #pragma unroll
            for (int j = 0; j < 4; ++j) {
                int d = c4 * 4 + j;
                Xt[d * 128 + (((m >> 3) ^ ((d >> 2) & 7)) << 3) + (m & 7)] = f2bf(fv[j]);
            }
        }
    }
    __syncthreads();

    u16* Og = Xagg + (size_t)batch * NN * DD;
    #pragma unroll
    for (int dh = 0; dh < 2; ++dh) {
        f32x16 acc1[2][2];
        #pragma unroll
        for (int fi = 0; fi < 2; ++fi)
            #pragma unroll
            for (int fd = 0; fd < 2; ++fd)
                #pragma unroll
                for (int r = 0; r < 16; ++r)
                    acc1[fi][fd][r] = 0.f;

        #pragma unroll
        for (int ksl = 0; ksl < 8; ++ksl) {
            const int kc = ksl * 2 + lh;
            bf16x8 af[2], bx[2];
            #pragma unroll
            for (int fi = 0; fi < 2; ++fi) {
                int i = wm * 64 + fi * 32 + l31;
                af[fi] = *(const bf16x8*)(Ms + i * 128 + ((kc ^ (i & 15)) << 3));
            }
            #pragma unroll
            for (int fd = 0; fd < 2; ++fd) {
                int d = dh * 256 + wn * 64 + fd * 32 + l31;
                bx[fd] = *(const bf16x8*)(Xt + d * 128 + ((kc ^ ((d >> 2) & 7)) << 3));
            }
            #pragma unroll
            for (int fi = 0; fi < 2; ++fi)
                #pragma unroll
                for (int fd = 0; fd < 2; ++fd)
                    acc1[fi][fd] = __builtin_amdgcn_mfma_f32_32x32x16_bf16(af[fi], bx[fd], acc1[fi][fd], 0, 0, 0);
        }

        #pragma unroll
        for (int fi = 0; fi < 2; ++fi)
            #pragma unroll
            for (int r = 0; r < 16; ++r) {
                int i = wm * 64 + fi * 32 + (r & 3) + 8 * (r >> 2) + 4 * lh;
                #pragma unroll
                for (int fd = 0; fd < 2; ++fd) {
                    int d = dh * 256 + wn * 64 + fd * 32 + l31;
                    Og[(size_t)i * DD + d] = f2bf(acc1[fi][fd][r]);
                }
            }
    }
}

// ---------------- out = sigmoid(LN( Xagg @ W^T + bias )) ----------------
// grid 1024 (M-tile 32), 256 thr = 4 waves; wave w -> h strip [128w, 128w+128).
// R20 config ((256,3): VGPR cap ~168, 12 waves/CU, 32 KB LDS, W-direct from Wt).
// NEW vs R20: sched_barrier(0) pipeline — issue step st+1's loads, FENCE, then
// run step st's MFMA cluster. Fence pins load issue-order without creating a
// use (no waitcnt before the MFMAs); the prefetched loads' waitcnt lands at
// their use one half-iteration later -> loads fly under the 32-cyc MFMA cluster.
// Wave-private register loads: no cross-wave hazard, replay-safe.
__global__ __launch_bounds__(256, 3) void gemm_ln_kernel(const u16* __restrict__ Xagg, const u16* __restrict__ Wt,
                                                         const float* __restrict__ bias, const float* __restrict__ lnw,
                                                         const float* __restrict__ lnb, float* __restrict__ out) {
    __shared__ __align__(16) char smem[32768];   // X tile; stats overlay after K-loop
    float* Pss = (float*)smem;                   // [4 w][32 row][2]
    float* musig = (float*)(smem + 1024);        // [32 row][2]

    const int t = threadIdx.x;
    const int lane = t & 63, w = t >> 6, l31 = lane & 31, lh = lane >> 5;
    const size_t rb = (size_t)blockIdx.x * 32;
    const u16* Xab = Xagg + rb * DD;

    float bias_v[4], lnw_v[4], lnb_v[4];
    #pragma unroll
    for (int fh = 0; fh < 4; ++fh) {
        int h = w * 128 + fh * 32 + l31;
        bias_v[fh] = bias[h];
        lnw_v[fh] = lnw[h];
        lnb_v[fh] = lnb[h];
    }

    // stage X tile once: linear LDS dest, inverse-swizzled source (c' = c ^ (m&15))
    #pragma unroll
    for (int it = 0; it < 8; ++it) {
        int q = it * 256 + t;
        int m = q >> 6, cp = q & 63;
        gload16(Xab + (size_t)m * DD + ((cp ^ (m & 15)) * 8), (u16*)smem + q * 8);
    }
    __syncthreads();   // drains gloads; X read-only hereafter

    f32x16 acc[4];
    #pragma unroll
    for (int fh = 0; fh < 4; ++fh)
        #pragma unroll
        for (int r = 0; r < 16; ++r)
            acc[fh][r] = 0.f;

    const u16* al = (const u16*)smem;
    const int hb = w * 128 + l31;

#define LOADF(AF, B0, B1, B2, B3, ST)                                              \
    {                                                                              \
        const int gc_ = (ST) * 2 + lh;                                             \
        AF = *(const bf16x8*)(al + (l31 * 64 + (gc_ ^ (l31 & 15))) * 8);           \
        const u16* wb_ = Wt + (size_t)gc_ * (HH * 8);                              \
        B0 = *(const bf16x8*)(wb_ + (hb + 0) * 8);                                 \
        B1 = *(const bf16x8*)(wb_ + (hb + 32) * 8);                                \
        B2 = *(const bf16x8*)(wb_ + (hb + 64) * 8);                                \
        B3 = *(const bf16x8*)(wb_ + (hb + 96) * 8);                                \
    }

    bf16x8 afA, bA0, bA1, bA2, bA3;
    bf16x8 afB, bB0, bB1, bB2, bB3;
    LOADF(afA, bA0, bA1, bA2, bA3, 0);
    #pragma unroll
    for (int st = 0; st < 32; st += 2) {
        LOADF(afB, bB0, bB1, bB2, bB3, st + 1);
        __builtin_amdgcn_sched_barrier(0);   // pin: B-loads issued before A-MFMAs
        acc[0] = __builtin_amdgcn_mfma_f32_32x32x16_bf16(afA, bA0, acc[0], 0, 0, 0);
        acc[1] = __builtin_amdgcn_mfma_f32_32x32x16_bf16(afA, bA1, acc[1], 0, 0, 0);
        acc[2] = __builtin_amdgcn_mfma_f32_32x32x16_bf16(afA, bA2, acc[2], 0, 0, 0);
        acc[3] = __builtin_amdgcn_mfma_f32_32x32x16_bf16(afA, bA3, acc[3], 0, 0, 0);
        if (st + 2 < 32) LOADF(afA, bA0, bA1, bA2, bA3, st + 2);
        __builtin_amdgcn_sched_barrier(0);   // pin: A-loads issued before B-MFMAs
        acc[0] = __builtin_amdgcn_mfma_f32_32x32x16_bf16(afB, bB0, acc[0], 0, 0, 0);
        acc[1] = __builtin_amdgcn_mfma_f32_32x32x16_bf16(afB, bB1, acc[1], 0, 0, 0);
        acc[2] = __builtin_amdgcn_mfma_f32_32x32x16_bf16(afB, bB2, acc[2], 0, 0, 0);
        acc[3] = __builtin_amdgcn_mfma_f32_32x32x16_bf16(afB, bB3, acc[3], 0, 0, 0);
    }
#undef LOADF
    __syncthreads();   // X dead; overlay stats

    // bias + per-row stats over this wave's 128 h  (R16/R20-verified epilogue)
    float rs[16], rss[16];
    #pragma unroll
    for (int r = 0; r < 16; ++r) {
        float s = 0.f, ss = 0.f;
        #pragma unroll
        for (int fh = 0; fh < 4; ++fh) {
            float a = acc[fh][r] + bias_v[fh];
            acc[fh][r] = a;
            s += a; ss += a * a;
        }
        rs[r] = s; rss[r] = ss;
    }
    #pragma unroll
    for (int msk = 1; msk <= 16; msk <<= 1)
        #pragma unroll
        for (int r = 0; r < 16; ++r) {
            rs[r] += __shfl_xor(rs[r], msk);
            rss[r] += __shfl_xor(rss[r], msk);
        }
    if (l31 == 0) {
        #pragma unroll
        for (int r = 0; r < 16; ++r) {
            int rl = (r & 3) + 8 * (r >> 2) + 4 * lh;
            float2 v; v.x = rs[r]; v.y = rss[r];
            *(float2*)(Pss + (w * 32 + rl) * 2) = v;
        }
    }
    __syncthreads();
    if (t < 32) {
        float s = 0.f, ss = 0.f;
        #pragma unroll
        for (int q = 0; q < 4; ++q) {
            float2 v = *(const float2*)(Pss + (q * 32 + t) * 2);
            s += v.x; ss += v.y;
        }
        float mean = s * (1.0f / 512.0f);
        float var = ss * (1.0f / 512.0f) - mean * mean;
        float2 mz; mz.x = mean; mz.y = rsqrtf(var + 1e-5f);
        *(float2*)(musig + t * 2) = mz;
    }
    __syncthreads();

    #pragma unroll
    for (int r = 0; r < 16; ++r) {
        int rl = (r & 3) + 8 * (r >> 2) + 4 * lh;
        float2 mz = *(const float2*)(musig + rl * 2);
        #pragma unroll
        for (int fh = 0; fh < 4; ++fh) {
            float xn = (acc[fh][r] - mz.x) * mz.y * lnw_v[fh] + lnb_v[fh];
            out[(rb + rl) * HH + w * 128 + fh * 32 + l31] = 1.0f / (1.0f + __expf(-xn));
        }
    }
}

extern "C" void kernel_launch(void* const* d_in, const int* in_sizes, int n_in,
                              void* d_out, int out_size, void* d_ws, size_t ws_size,
                              hipStream_t stream) {
    const float* X = (const float*)d_in[0];
    const float* A = (const float*)d_in[1];
    const float* W = (const float*)d_in[2];
    const float* bias = (const float*)d_in[3];
    const float* lnw = (const float*)d_in[4];
    const float* lnb = (const float*)d_in[5];
    float* out = (float*)d_out;

    u16* Xagg = (u16*)d_ws;                                  // B*N*D bf16 = 32 MB
    u16* Wt = (u16*)d_ws + (size_t)BB * NN * DD;             // transposed W bf16 = 512 KB

    hipLaunchKernelGGL(wconv_kernel, dim3(256), dim3(256), 0, stream, W, Wt);
    hipLaunchKernelGGL(agg_kernel, dim3(256), dim3(512), 0, stream, X, A, Xagg);
    hipLaunchKernelGGL(gemm_ln_kernel, dim3(1024), dim3(256), 0, stream, Xagg, Wt, bias, lnw, lnb, out);
}